// Round 10
// baseline (213.358 us; speedup 1.0000x reference)
//
#include <hip/hip_runtime.h>

// 2-layer GCN: h1 = emb[x] @ W1; agg+b1+relu; @ W2; agg+b2.
// CSR built per-launch via two-level binned counting sort (no global atomics).
// R10: 16B-per-lane gathers (one dwordx4 = 16 rows agg1 / 32 rows agg2 in
// flight -- 2x R9's MLP at fewer VALU); BINSHIFT 8 (64B binscatter runs);
// int4 edge reads; mm1 fused into binsort's per-bin epilogue.

#define BS   256
#define NBLK 256          // blocks for hist/binscatter (MUST stay 256: idx>>8==bin)
#define BINSHIFT 8        // 256 nodes per bin
#define BIN  256
#define MAXBINS 512
#define BINCAP 4608       // LDS packed staging (mean bin = 4096, sigma ~64)

union H2 { int i; _Float16 h[2]; };

// ---- pass A: per-block histograms of dst bins (int4 reads, grid-stride) -----
__global__ void k_hist(const int* __restrict__ dst, int E, int NBINS,
                       int* __restrict__ histG) {
    __shared__ int h[MAXBINS];
    int t = threadIdx.x;
    for (int i = t; i < NBINS; i += BS) h[i] = 0;
    __syncthreads();
    int E4 = E >> 2;
    const int4* d4 = (const int4*)dst;
    for (int i = blockIdx.x * BS + t; i < E4; i += NBLK * BS) {
        int4 d = d4[i];
        atomicAdd(&h[d.x >> BINSHIFT], 1);
        atomicAdd(&h[d.y >> BINSHIFT], 1);
        atomicAdd(&h[d.z >> BINSHIFT], 1);
        atomicAdd(&h[d.w >> BINSHIFT], 1);
    }
    if (blockIdx.x == 0 && t < (E & 3))
        atomicAdd(&h[dst[(E4 << 2) + t] >> BINSHIFT], 1);
    __syncthreads();
    for (int i = t; i < NBINS; i += BS) histG[i * NBLK + blockIdx.x] = h[i];
}

// ---- hierarchical exclusive scan over L = NBINS*NBLK ints -------------------
__global__ void k_scanA(const int* __restrict__ in, int L,
                        int* __restrict__ partial, int* __restrict__ bsum) {
    __shared__ int s[BS];
    int t = threadIdx.x;
    int i = blockIdx.x * BS + t;
    int v = (i < L) ? in[i] : 0;
    s[t] = v;
    __syncthreads();
    for (int off = 1; off < BS; off <<= 1) {
        int add = (t >= off) ? s[t - off] : 0;
        __syncthreads();
        s[t] += add;
        __syncthreads();
    }
    if (i < L) partial[i] = s[t] - v;
    if (t == BS - 1) bsum[blockIdx.x] = s[BS - 1];
}

__global__ void k_scanB(const int* __restrict__ bsum, int nB, int* __restrict__ boff) {
    __shared__ int s[BS];
    int t = threadIdx.x;
    int PER = (nB + BS - 1) / BS;
    int loc[8];
    int base = t * PER;
    int sum = 0;
    for (int j = 0; j < PER && j < 8; j++) {
        int idx = base + j;
        int v = (idx < nB) ? bsum[idx] : 0;
        loc[j] = sum;
        sum += v;
    }
    s[t] = sum;
    __syncthreads();
    for (int off = 1; off < BS; off <<= 1) {
        int add = (t >= off) ? s[t - off] : 0;
        __syncthreads();
        s[t] += add;
        __syncthreads();
    }
    int ex = s[t] - sum;
    for (int j = 0; j < PER && j < 8; j++) {
        int idx = base + j;
        if (idx < nB) boff[idx] = ex + loc[j];
    }
}

// ---- pass C: scatter edges into bin-partitioned order (LDS cursors only) ----
// ONE packed 4B write per edge: src | dstLocal<<18  (src < 2^18).
__global__ void k_binscatter(const int* __restrict__ src, const int* __restrict__ dst,
                             int E, int NBINS, const int* __restrict__ partial,
                             const int* __restrict__ boff, int* __restrict__ packed) {
    __shared__ int cur[MAXBINS];
    int t = threadIdx.x;
    for (int i = t; i < NBINS; i += BS)
        cur[i] = partial[i * NBLK + blockIdx.x] + boff[i];
    __syncthreads();
    int E4 = E >> 2;
    const int4* s4 = (const int4*)src;
    const int4* d4 = (const int4*)dst;
    for (int i = blockIdx.x * BS + t; i < E4; i += NBLK * BS) {
        int4 s = s4[i];
        int4 d = d4[i];
        int p0 = atomicAdd(&cur[d.x >> BINSHIFT], 1);
        packed[p0] = s.x | ((d.x & (BIN - 1)) << 18);
        int p1 = atomicAdd(&cur[d.y >> BINSHIFT], 1);
        packed[p1] = s.y | ((d.y & (BIN - 1)) << 18);
        int p2 = atomicAdd(&cur[d.z >> BINSHIFT], 1);
        packed[p2] = s.z | ((d.z & (BIN - 1)) << 18);
        int p3 = atomicAdd(&cur[d.w >> BINSHIFT], 1);
        packed[p3] = s.w | ((d.w & (BIN - 1)) << 18);
    }
    if (blockIdx.x == 0 && t < (E & 3)) {
        int e = (E4 << 2) + t;
        int d = dst[e];
        int p = atomicAdd(&cur[d >> BINSHIFT], 1);
        packed[p] = src[e] | ((d & (BIN - 1)) << 18);
    }
}

// ---- pass D: per-bin counting sort (staged in LDS) + fused mm1 --------------
// sig1[n][c] = dinv[n] * (emb[x[n]] @ W1)[c], fp16, written per bin-block.
__global__ void k_binsort(const int* __restrict__ packed,
                          const int* __restrict__ partial, const int* __restrict__ boff,
                          int NBINS, int N, int E,
                          const int* __restrict__ x, const float* __restrict__ emb,
                          const float* __restrict__ W1,
                          int* __restrict__ row_start, float* __restrict__ dinv,
                          int* __restrict__ col, _Float16* __restrict__ sig1) {
    __shared__ int buf[BINCAP];                  // 18 KB staging
    __shared__ int ldeg[BIN];
    __shared__ int lrs[BIN];
    __shared__ int cur[BIN];
    __shared__ float sW[512];                    // W1 (16x32)
    int b = blockIdx.x;
    int t = threadIdx.x;
    int node0 = b << BINSHIFT;
    int e0 = partial[b * NBLK] + boff[b];
    int e1 = (b + 1 < NBINS) ? (partial[(b + 1) * NBLK] + boff[b + 1]) : E;
    int cnt = e1 - e0;
    bool fits = (cnt <= BINCAP);                 // uniform per block
    if (b == 0 && t == 0) row_start[N] = E;      // sentinel
    sW[t] = W1[t];
    sW[t + 256] = W1[t + 256];
    ldeg[t] = 0;
    if (fits)
        for (int i = t; i < cnt; i += BS) buf[i] = packed[e0 + i];
    __syncthreads();
    for (int i = t; i < cnt; i += BS) {
        int v = fits ? buf[i] : packed[e0 + i];
        atomicAdd(&ldeg[((unsigned)v >> 18) & (BIN - 1)], 1);
    }
    __syncthreads();
    lrs[t] = ldeg[t];
    __syncthreads();
    for (int off = 1; off < BIN; off <<= 1) {
        int add = (t >= off) ? lrs[t - off] : 0;
        __syncthreads();
        lrs[t] += add;
        __syncthreads();
    }
    int myDeg = ldeg[t];
    int ex = lrs[t] - myDeg;
    cur[t] = ex;
    int n = node0 + t;                           // one node per thread
    float di = rsqrtf((float)(myDeg + 1));
    if (n < N) {
        row_start[n] = e0 + ex;
        dinv[n] = di;
    }
    __syncthreads();
    for (int i = t; i < cnt; i += BS) {
        int v = fits ? buf[i] : packed[e0 + i];
        int pos = atomicAdd(&cur[((unsigned)v >> 18) & (BIN - 1)], 1);
        col[e0 + pos] = v & 0x3FFFF;
    }
    // ---- fused mm1 for this bin's 256 nodes ----
    if (n < N) {
        const float4* er = (const float4*)(emb + (size_t)x[n] * 16);
        float4 ra = er[0], rb = er[1], rc = er[2], rd = er[3];
        float ev[16] = {ra.x, ra.y, ra.z, ra.w, rb.x, rb.y, rb.z, rb.w,
                        rc.x, rc.y, rc.z, rc.w, rd.x, rd.y, rd.z, rd.w};
        int4* s1o = (int4*)sig1;
        #pragma unroll
        for (int cq = 0; cq < 4; cq++) {
            H2 pk[4];
            #pragma unroll
            for (int dw = 0; dw < 4; dw++) {
                int c = cq * 8 + dw * 2;
                float acc0 = 0.f, acc1 = 0.f;
                #pragma unroll
                for (int k = 0; k < 16; k++) {
                    acc0 += ev[k] * sW[k * 32 + c];
                    acc1 += ev[k] * sW[k * 32 + c + 1];
                }
                pk[dw].h[0] = (_Float16)(acc0 * di);
                pk[dw].h[1] = (_Float16)(acc1 * di);
            }
            int4 pv;
            pv.x = pk[0].i; pv.y = pk[1].i; pv.z = pk[2].i; pv.w = pk[3].i;
            s1o[(size_t)n * 4 + cq] = pv;
        }
    }
}

// ---- fused layer-1 aggregate + b1 + relu + GEMM W2 -> sig2 (fp16) -----------
// one WAVE per node; lanes = (edge-group gg in [0,16)) x (16B quad q in [0,4)).
// one dwordx4 gather = 16 full rows; 2 per iter = 32 rows in flight per wave.
__global__ __launch_bounds__(BS) void k_agg1mm2(
    const _Float16* __restrict__ sig1, const int* __restrict__ row_start,
    const float* __restrict__ dinv, const int* __restrict__ col,
    const float* __restrict__ b1, const float* __restrict__ W2,
    int N, _Float16* __restrict__ sig2) {
    __shared__ float sW[32][17];
    __shared__ float hbuf[4][32];                // per-wave h vector
    int t = threadIdx.x;
    sW[t >> 4][t & 15] = W2[t];
    sW[(t >> 4) + 16][t & 15] = W2[t + 256];
    __syncthreads();
    int lane = t & 63;
    int wid = t >> 6;
    int n = blockIdx.x * 4 + wid;
    if (n >= N) return;
    int q  = lane & 3;                 // 16B quad within 64B row
    int gg = lane >> 2;                // edge subgroup 0..15
    int l32 = lane & 31;
    const int4* s1 = (const int4*)sig1;
    int rs = __builtin_amdgcn_readfirstlane(row_start[n]);
    int re = __builtin_amdgcn_readfirstlane(row_start[n + 1]);
    int dn = re - rs;
    float a0 = 0.f, a1 = 0.f, a2 = 0.f, a3 = 0.f;
    float a4 = 0.f, a5 = 0.f, a6 = 0.f, a7 = 0.f;
    int iters = (dn + 31) >> 5;
    int colv = 0;
    if (iters > 0) {
        int idx = l32 > dn - 1 ? dn - 1 : l32;
        colv = col[rs + idx];
    }
    for (int it = 0; it < iters; it++) {
        int e = it << 5;
        int coln = 0;
        if (it + 1 < iters) {
            int idx = e + 32 + l32; if (idx > dn - 1) idx = dn - 1;
            coln = col[rs + idx];              // prefetch next round
        }
        int sa = __shfl(colv, gg);
        int sb = __shfl(colv, 16 + gg);
        int4 ua = s1[(size_t)sa * 4 + q];      // 16 rows in flight
        int4 ub = s1[(size_t)sb * 4 + q];      // 16 more
        float ma = (e + gg < dn) ? 1.f : 0.f;
        float mb = (e + 16 + gg < dn) ? 1.f : 0.f;
        H2 p0, p1, p2, p3;
        p0.i = ua.x; p1.i = ua.y; p2.i = ua.z; p3.i = ua.w;
        a0 = fmaf(ma, (float)p0.h[0], a0); a1 = fmaf(ma, (float)p0.h[1], a1);
        a2 = fmaf(ma, (float)p1.h[0], a2); a3 = fmaf(ma, (float)p1.h[1], a3);
        a4 = fmaf(ma, (float)p2.h[0], a4); a5 = fmaf(ma, (float)p2.h[1], a5);
        a6 = fmaf(ma, (float)p3.h[0], a6); a7 = fmaf(ma, (float)p3.h[1], a7);
        p0.i = ub.x; p1.i = ub.y; p2.i = ub.z; p3.i = ub.w;
        a0 = fmaf(mb, (float)p0.h[0], a0); a1 = fmaf(mb, (float)p0.h[1], a1);
        a2 = fmaf(mb, (float)p1.h[0], a2); a3 = fmaf(mb, (float)p1.h[1], a3);
        a4 = fmaf(mb, (float)p2.h[0], a4); a5 = fmaf(mb, (float)p2.h[1], a5);
        a6 = fmaf(mb, (float)p3.h[0], a6); a7 = fmaf(mb, (float)p3.h[1], a7);
        colv = coln;
    }
    // reduce over gg (lane bits 2..5)
    #pragma unroll
    for (int d = 4; d <= 32; d <<= 1) {
        a0 += __shfl_xor(a0, d); a1 += __shfl_xor(a1, d);
        a2 += __shfl_xor(a2, d); a3 += __shfl_xor(a3, d);
        a4 += __shfl_xor(a4, d); a5 += __shfl_xor(a5, d);
        a6 += __shfl_xor(a6, d); a7 += __shfl_xor(a7, d);
    }
    {   // self-loop (pre-scaled row)
        int4 us = s1[(size_t)n * 4 + q];
        H2 p0, p1, p2, p3;
        p0.i = us.x; p1.i = us.y; p2.i = us.z; p3.i = us.w;
        a0 += (float)p0.h[0]; a1 += (float)p0.h[1];
        a2 += (float)p1.h[0]; a3 += (float)p1.h[1];
        a4 += (float)p2.h[0]; a5 += (float)p2.h[1];
        a6 += (float)p3.h[0]; a7 += (float)p3.h[1];
    }
    float di = dinv[n];
    float4 bA = ((const float4*)b1)[2 * q];
    float4 bB = ((const float4*)b1)[2 * q + 1];
    float h0 = fmaxf(a0 * di + bA.x, 0.f), h1 = fmaxf(a1 * di + bA.y, 0.f);
    float h2 = fmaxf(a2 * di + bA.z, 0.f), h3 = fmaxf(a3 * di + bA.w, 0.f);
    float h4 = fmaxf(a4 * di + bB.x, 0.f), h5 = fmaxf(a5 * di + bB.y, 0.f);
    float h6 = fmaxf(a6 * di + bB.z, 0.f), h7 = fmaxf(a7 * di + bB.w, 0.f);
    if (gg == 0) {                     // lanes 0..3 hold q=0..3 (all replicas equal)
        float4* hb = (float4*)&hbuf[wid][8 * q];
        hb[0] = make_float4(h0, h1, h2, h3);
        hb[1] = make_float4(h4, h5, h6, h7);
    }
    // same-wave LDS dependency: compiler inserts lgkmcnt wait (no barrier;
    // hbuf is per-wave so no cross-wave hazard)
    int co = lane & 15;
    int kh = lane >> 4;                // split-k quarter 0..3
    float a = 0.f;
    #pragma unroll
    for (int j = 0; j < 8; j++)
        a += hbuf[wid][8 * kh + j] * sW[8 * kh + j][co];
    a += __shfl_xor(a, 16);
    a += __shfl_xor(a, 32);
    if (lane < 16) sig2[(size_t)n * 16 + co] = (_Float16)(a * di);   // pre-scale
}

// ---- layer-2 aggregate + b2 -> out ------------------------------------------
// one WAVE per node; lanes = (edge-group gg in [0,32)) x (16B half q in [0,2)).
// one dwordx4 gather = 32 full rows in flight; avg-degree node = 1 iter.
__global__ __launch_bounds__(BS) void k_agg2(
    const _Float16* __restrict__ sig2, const int* __restrict__ row_start,
    const float* __restrict__ dinv, const int* __restrict__ col,
    const float* __restrict__ b2, int N, float* __restrict__ out) {
    int t = threadIdx.x;
    int lane = t & 63;
    int n = blockIdx.x * 4 + (t >> 6);
    if (n >= N) return;
    int q  = lane & 1;                 // 16B half of 32B row
    int gg = lane >> 1;                // edge group 0..31
    int l32 = lane & 31;
    const int4* s2 = (const int4*)sig2;
    int rs = __builtin_amdgcn_readfirstlane(row_start[n]);
    int re = __builtin_amdgcn_readfirstlane(row_start[n + 1]);
    int dn = re - rs;
    float a0 = 0.f, a1 = 0.f, a2 = 0.f, a3 = 0.f;
    float a4 = 0.f, a5 = 0.f, a6 = 0.f, a7 = 0.f;
    int iters = (dn + 31) >> 5;
    int colv = 0;
    if (iters > 0) {
        int idx = l32 > dn - 1 ? dn - 1 : l32;
        colv = col[rs + idx];
    }
    for (int it = 0; it < iters; it++) {
        int e = it << 5;
        int coln = 0;
        if (it + 1 < iters) {
            int idx = e + 32 + l32; if (idx > dn - 1) idx = dn - 1;
            coln = col[rs + idx];
        }
        int s = __shfl(colv, gg);
        int4 u = s2[(size_t)s * 2 + q];        // 32 rows in flight
        float m = (e + gg < dn) ? 1.f : 0.f;
        H2 p0, p1, p2, p3;
        p0.i = u.x; p1.i = u.y; p2.i = u.z; p3.i = u.w;
        a0 = fmaf(m, (float)p0.h[0], a0); a1 = fmaf(m, (float)p0.h[1], a1);
        a2 = fmaf(m, (float)p1.h[0], a2); a3 = fmaf(m, (float)p1.h[1], a3);
        a4 = fmaf(m, (float)p2.h[0], a4); a5 = fmaf(m, (float)p2.h[1], a5);
        a6 = fmaf(m, (float)p3.h[0], a6); a7 = fmaf(m, (float)p3.h[1], a7);
        colv = coln;
    }
    // reduce over gg (lane bits 1..5)
    #pragma unroll
    for (int d = 2; d <= 32; d <<= 1) {
        a0 += __shfl_xor(a0, d); a1 += __shfl_xor(a1, d);
        a2 += __shfl_xor(a2, d); a3 += __shfl_xor(a3, d);
        a4 += __shfl_xor(a4, d); a5 += __shfl_xor(a5, d);
        a6 += __shfl_xor(a6, d); a7 += __shfl_xor(a7, d);
    }
    {   // self-loop
        int4 us = s2[(size_t)n * 2 + q];
        H2 p0, p1, p2, p3;
        p0.i = us.x; p1.i = us.y; p2.i = us.z; p3.i = us.w;
        a0 += (float)p0.h[0]; a1 += (float)p0.h[1];
        a2 += (float)p1.h[0]; a3 += (float)p1.h[1];
        a4 += (float)p2.h[0]; a5 += (float)p2.h[1];
        a6 += (float)p3.h[0]; a7 += (float)p3.h[1];
    }
    if (gg == 0) {                     // lanes 0..1 write channels 8q..8q+7
        float di = dinv[n];
        float4 bA = ((const float4*)b2)[2 * q];
        float4 bB = ((const float4*)b2)[2 * q + 1];
        float4 oA = make_float4(a0 * di + bA.x, a1 * di + bA.y,
                                a2 * di + bA.z, a3 * di + bA.w);
        float4 oB = make_float4(a4 * di + bB.x, a5 * di + bB.y,
                                a6 * di + bB.z, a7 * di + bB.w);
        float4* op = (float4*)out;
        op[(size_t)n * 4 + 2 * q] = oA;
        op[(size_t)n * 4 + 2 * q + 1] = oB;
    }
}

extern "C" void kernel_launch(void* const* d_in, const int* in_sizes, int n_in,
                              void* d_out, int out_size, void* d_ws, size_t ws_size,
                              hipStream_t stream) {
    const int*   x   = (const int*)d_in[0];
    const int*   ei  = (const int*)d_in[1];
    const float* emb = (const float*)d_in[2];
    const float* W1  = (const float*)d_in[3];
    const float* b1  = (const float*)d_in[4];
    const float* W2  = (const float*)d_in[5];
    const float* b2  = (const float*)d_in[6];
    float* out = (float*)d_out;

    const int N = in_sizes[0];
    const int E = in_sizes[1] / 2;
    const int* srcp = ei;
    const int* dstp = ei + E;
    const int NBINS = (N + BIN - 1) >> BINSHIFT;   // 391 for N=100000
    const int L = NBINS * NBLK;
    const int nB2 = (L + BS - 1) / BS;

    auto al = [](size_t b) { return (b + 255) & ~size_t(255); };
    char* w = (char*)d_ws;
    auto carve = [&](size_t bytes) {
        void* p = (void*)w;
        w += al(bytes);
        return p;
    };
    // no unions: binsort writes sig1 while other blocks still read packed.
    int*   row_start = (int*)carve((size_t)(N + 1) * 4);
    float* dinv      = (float*)carve((size_t)N * 4);
    int*   col       = (int*)carve((size_t)E * 4);
    int*   histG     = (int*)carve((size_t)L * 4);
    int*   partial   = (int*)carve((size_t)L * 4);
    int*   bsum      = (int*)carve((size_t)nB2 * 4);
    int*   boff      = (int*)carve((size_t)nB2 * 4);
    int*   packed    = (int*)carve((size_t)E * 4);
    _Float16* sig1   = (_Float16*)carve((size_t)N * 32 * 2);
    _Float16* sig2   = (_Float16*)carve((size_t)N * 16 * 2);
    (void)ws_size; (void)n_in; (void)out_size;

    int gL = (L + BS - 1) / BS;
    k_hist<<<NBLK, BS, 0, stream>>>(dstp, E, NBINS, histG);
    k_scanA<<<gL, BS, 0, stream>>>(histG, L, partial, bsum);
    k_scanB<<<1, BS, 0, stream>>>(bsum, nB2, boff);
    k_binscatter<<<NBLK, BS, 0, stream>>>(srcp, dstp, E, NBINS, partial, boff, packed);
    k_binsort<<<NBINS, BS, 0, stream>>>(packed, partial, boff, NBINS, N, E,
                                        x, emb, W1, row_start, dinv, col, sig1);

    int gW = (N + 3) / 4;              // one wave (64 lanes) per node
    k_agg1mm2<<<gW, BS, 0, stream>>>(sig1, row_start, dinv, col, b1, W2, N, sig2);
    k_agg2<<<gW, BS, 0, stream>>>(sig2, row_start, dinv, col, b2, N, out);
}

// Round 11
// 180.820 us; speedup vs baseline: 1.1799x; 1.1799x over previous
//
#include <hip/hip_runtime.h>

// 2-layer GCN: h1 = emb[x] @ W1; agg+b1+relu; @ W2; agg+b2.
// CSR built per-launch via two-level binned counting sort (no global atomics).
// R11 = R9 agg kernels (dword gathers, 4-rows/inst, masked single-round
// loops -- R10's 16B-gather layout regressed: 16 divergent lines per inst +
// 8-acc reductions pushed VALUBusy to 52%) + R10 build side (int4 edge
// reads, 256-node bins, mm1 fused into binsort).

#define BS   256
#define NBLK 256          // blocks for hist/binscatter (MUST stay 256: idx>>8==bin)
#define BINSHIFT 8        // 256 nodes per bin
#define BIN  256
#define MAXBINS 512
#define BINCAP 4608       // LDS packed staging (mean bin = 4092, sigma ~64)

union H2 { int i; _Float16 h[2]; };

// ---- pass A: per-block histograms of dst bins (int4 reads, grid-stride) -----
__global__ void k_hist(const int* __restrict__ dst, int E, int NBINS,
                       int* __restrict__ histG) {
    __shared__ int h[MAXBINS];
    int t = threadIdx.x;
    for (int i = t; i < NBINS; i += BS) h[i] = 0;
    __syncthreads();
    int E4 = E >> 2;
    const int4* d4 = (const int4*)dst;
    for (int i = blockIdx.x * BS + t; i < E4; i += NBLK * BS) {
        int4 d = d4[i];
        atomicAdd(&h[d.x >> BINSHIFT], 1);
        atomicAdd(&h[d.y >> BINSHIFT], 1);
        atomicAdd(&h[d.z >> BINSHIFT], 1);
        atomicAdd(&h[d.w >> BINSHIFT], 1);
    }
    if (blockIdx.x == 0 && t < (E & 3))
        atomicAdd(&h[dst[(E4 << 2) + t] >> BINSHIFT], 1);
    __syncthreads();
    for (int i = t; i < NBINS; i += BS) histG[i * NBLK + blockIdx.x] = h[i];
}

// ---- hierarchical exclusive scan over L = NBINS*NBLK ints -------------------
__global__ void k_scanA(const int* __restrict__ in, int L,
                        int* __restrict__ partial, int* __restrict__ bsum) {
    __shared__ int s[BS];
    int t = threadIdx.x;
    int i = blockIdx.x * BS + t;
    int v = (i < L) ? in[i] : 0;
    s[t] = v;
    __syncthreads();
    for (int off = 1; off < BS; off <<= 1) {
        int add = (t >= off) ? s[t - off] : 0;
        __syncthreads();
        s[t] += add;
        __syncthreads();
    }
    if (i < L) partial[i] = s[t] - v;
    if (t == BS - 1) bsum[blockIdx.x] = s[BS - 1];
}

__global__ void k_scanB(const int* __restrict__ bsum, int nB, int* __restrict__ boff) {
    __shared__ int s[BS];
    int t = threadIdx.x;
    int PER = (nB + BS - 1) / BS;
    int loc[8];
    int base = t * PER;
    int sum = 0;
    for (int j = 0; j < PER && j < 8; j++) {
        int idx = base + j;
        int v = (idx < nB) ? bsum[idx] : 0;
        loc[j] = sum;
        sum += v;
    }
    s[t] = sum;
    __syncthreads();
    for (int off = 1; off < BS; off <<= 1) {
        int add = (t >= off) ? s[t - off] : 0;
        __syncthreads();
        s[t] += add;
        __syncthreads();
    }
    int ex = s[t] - sum;
    for (int j = 0; j < PER && j < 8; j++) {
        int idx = base + j;
        if (idx < nB) boff[idx] = ex + loc[j];
    }
}

// ---- pass C: scatter edges into bin-partitioned order (LDS cursors only) ----
// ONE packed 4B write per edge: src | dstLocal<<18  (src < 2^18).
__global__ void k_binscatter(const int* __restrict__ src, const int* __restrict__ dst,
                             int E, int NBINS, const int* __restrict__ partial,
                             const int* __restrict__ boff, int* __restrict__ packed) {
    __shared__ int cur[MAXBINS];
    int t = threadIdx.x;
    for (int i = t; i < NBINS; i += BS)
        cur[i] = partial[i * NBLK + blockIdx.x] + boff[i];
    __syncthreads();
    int E4 = E >> 2;
    const int4* s4 = (const int4*)src;
    const int4* d4 = (const int4*)dst;
    for (int i = blockIdx.x * BS + t; i < E4; i += NBLK * BS) {
        int4 s = s4[i];
        int4 d = d4[i];
        int p0 = atomicAdd(&cur[d.x >> BINSHIFT], 1);
        packed[p0] = s.x | ((d.x & (BIN - 1)) << 18);
        int p1 = atomicAdd(&cur[d.y >> BINSHIFT], 1);
        packed[p1] = s.y | ((d.y & (BIN - 1)) << 18);
        int p2 = atomicAdd(&cur[d.z >> BINSHIFT], 1);
        packed[p2] = s.z | ((d.z & (BIN - 1)) << 18);
        int p3 = atomicAdd(&cur[d.w >> BINSHIFT], 1);
        packed[p3] = s.w | ((d.w & (BIN - 1)) << 18);
    }
    if (blockIdx.x == 0 && t < (E & 3)) {
        int e = (E4 << 2) + t;
        int d = dst[e];
        int p = atomicAdd(&cur[d >> BINSHIFT], 1);
        packed[p] = src[e] | ((d & (BIN - 1)) << 18);
    }
}

// ---- pass D: per-bin counting sort (staged in LDS) + fused mm1 --------------
// sig1[n][c] = dinv[n] * (emb[x[n]] @ W1)[c], fp16, written per bin-block.
__global__ void k_binsort(const int* __restrict__ packed,
                          const int* __restrict__ partial, const int* __restrict__ boff,
                          int NBINS, int N, int E,
                          const int* __restrict__ x, const float* __restrict__ emb,
                          const float* __restrict__ W1,
                          int* __restrict__ row_start, float* __restrict__ dinv,
                          int* __restrict__ col, _Float16* __restrict__ sig1) {
    __shared__ int buf[BINCAP];                  // 18 KB staging
    __shared__ int ldeg[BIN];
    __shared__ int lrs[BIN];
    __shared__ int cur[BIN];
    __shared__ float sW[512];                    // W1 (16x32)
    int b = blockIdx.x;
    int t = threadIdx.x;
    int node0 = b << BINSHIFT;
    int e0 = partial[b * NBLK] + boff[b];
    int e1 = (b + 1 < NBINS) ? (partial[(b + 1) * NBLK] + boff[b + 1]) : E;
    int cnt = e1 - e0;
    bool fits = (cnt <= BINCAP);                 // uniform per block
    if (b == 0 && t == 0) row_start[N] = E;      // sentinel
    sW[t] = W1[t];
    sW[t + 256] = W1[t + 256];
    ldeg[t] = 0;
    if (fits)
        for (int i = t; i < cnt; i += BS) buf[i] = packed[e0 + i];
    __syncthreads();
    for (int i = t; i < cnt; i += BS) {
        int v = fits ? buf[i] : packed[e0 + i];
        atomicAdd(&ldeg[((unsigned)v >> 18) & (BIN - 1)], 1);
    }
    __syncthreads();
    lrs[t] = ldeg[t];
    __syncthreads();
    for (int off = 1; off < BIN; off <<= 1) {
        int add = (t >= off) ? lrs[t - off] : 0;
        __syncthreads();
        lrs[t] += add;
        __syncthreads();
    }
    int myDeg = ldeg[t];
    int ex = lrs[t] - myDeg;
    cur[t] = ex;
    int n = node0 + t;                           // one node per thread
    float di = rsqrtf((float)(myDeg + 1));
    if (n < N) {
        row_start[n] = e0 + ex;
        dinv[n] = di;
    }
    __syncthreads();
    for (int i = t; i < cnt; i += BS) {
        int v = fits ? buf[i] : packed[e0 + i];
        int pos = atomicAdd(&cur[((unsigned)v >> 18) & (BIN - 1)], 1);
        col[e0 + pos] = v & 0x3FFFF;
    }
    // ---- fused mm1 for this bin's 256 nodes ----
    if (n < N) {
        const float4* er = (const float4*)(emb + (size_t)x[n] * 16);
        float4 ra = er[0], rb = er[1], rc = er[2], rd = er[3];
        float ev[16] = {ra.x, ra.y, ra.z, ra.w, rb.x, rb.y, rb.z, rb.w,
                        rc.x, rc.y, rc.z, rc.w, rd.x, rd.y, rd.z, rd.w};
        int4* s1o = (int4*)sig1;
        #pragma unroll
        for (int cq = 0; cq < 4; cq++) {
            H2 pk[4];
            #pragma unroll
            for (int dw = 0; dw < 4; dw++) {
                int c = cq * 8 + dw * 2;
                float acc0 = 0.f, acc1 = 0.f;
                #pragma unroll
                for (int k = 0; k < 16; k++) {
                    acc0 += ev[k] * sW[k * 32 + c];
                    acc1 += ev[k] * sW[k * 32 + c + 1];
                }
                pk[dw].h[0] = (_Float16)(acc0 * di);
                pk[dw].h[1] = (_Float16)(acc1 * di);
            }
            int4 pv;
            pv.x = pk[0].i; pv.y = pk[1].i; pv.z = pk[2].i; pv.w = pk[3].i;
            s1o[(size_t)n * 4 + cq] = pv;
        }
    }
}

// ---- fused layer-1 aggregate + b1 + relu + GEMM W2 -> sig2 (fp16) -----------
// one WAVE per node; lanes = (edge-group g in [0,4)) x (dword-channel cd).
// masked single-round loop: ceil(dn/16) iters, clamped idx, 0/1 masks;
// col prefetched one iteration ahead (loads overlap gathers).  [R9 kernel]
__global__ __launch_bounds__(BS) void k_agg1mm2(
    const _Float16* __restrict__ sig1, const int* __restrict__ row_start,
    const float* __restrict__ dinv, const int* __restrict__ col,
    const float* __restrict__ b1, const float* __restrict__ W2,
    int N, _Float16* __restrict__ sig2) {
    __shared__ float sW[32][17];
    int t = threadIdx.x;
    sW[t >> 4][t & 15] = W2[t];
    sW[(t >> 4) + 16][t & 15] = W2[t + 256];
    __syncthreads();
    int lane = t & 63;
    int n = blockIdx.x * (BS / 64) + (t >> 6);
    if (n >= N) return;
    int g  = lane >> 4;              // edge group 0..3
    int cd = lane & 15;              // dword channel (2 fp16)
    const int* s1i = (const int*)sig1;
    int rs = __builtin_amdgcn_readfirstlane(row_start[n]);
    int re = __builtin_amdgcn_readfirstlane(row_start[n + 1]);
    int dn = re - rs;                // wave-uniform
    float a0 = 0.f, a1 = 0.f;
    int iters = (dn + 15) >> 4;
    int colv = 0;
    if (iters > 0) {
        int idx = cd; if (idx > dn - 1) idx = dn - 1;
        colv = col[rs + idx];
    }
    for (int it = 0; it < iters; it++) {
        int e = it << 4;
        int coln = 0;
        if (it + 1 < iters) {
            int idx = e + 16 + cd; if (idx > dn - 1) idx = dn - 1;
            coln = col[rs + idx];                // prefetch next round
        }
        int s0 = __shfl(colv, g);
        int s1 = __shfl(colv, 4 + g);
        int s2 = __shfl(colv, 8 + g);
        int s3 = __shfl(colv, 12 + g);
        H2 u0, u1, u2, u3;
        u0.i = s1i[s0 * 16 + cd];                // 4 rows (64B) in flight
        u1.i = s1i[s1 * 16 + cd];
        u2.i = s1i[s2 * 16 + cd];
        u3.i = s1i[s3 * 16 + cd];
        float m0 = (e + g      < dn) ? 1.f : 0.f;
        float m1 = (e + 4 + g  < dn) ? 1.f : 0.f;
        float m2 = (e + 8 + g  < dn) ? 1.f : 0.f;
        float m3 = (e + 12 + g < dn) ? 1.f : 0.f;
        a0 += (m0 * (float)u0.h[0] + m1 * (float)u1.h[0])
            + (m2 * (float)u2.h[0] + m3 * (float)u3.h[0]);
        a1 += (m0 * (float)u0.h[1] + m1 * (float)u1.h[1])
            + (m2 * (float)u2.h[1] + m3 * (float)u3.h[1]);
        colv = coln;
    }
    a0 += __shfl_xor(a0, 16); a0 += __shfl_xor(a0, 32);
    a1 += __shfl_xor(a1, 16); a1 += __shfl_xor(a1, 32);
    H2 us; us.i = s1i[n * 16 + cd];              // self-loop (pre-scaled)
    a0 += (float)us.h[0];
    a1 += (float)us.h[1];
    float di = dinv[n];
    float2 b = ((const float2*)b1)[cd];
    float h0 = fmaxf(a0 * di + b.x, 0.f);
    float h1 = fmaxf(a1 * di + b.y, 0.f);
    // 4-way split-k in-wave GEMM: group g sums k in [8g, 8g+8)
    float a = 0.f;
    #pragma unroll
    for (int j = 0; j < 4; j++) {
        int cdk = 4 * g + j;
        float hk0 = __shfl(h0, cdk);
        float hk1 = __shfl(h1, cdk);
        a += hk0 * sW[2 * cdk][cd] + hk1 * sW[2 * cdk + 1][cd];
    }
    a += __shfl_xor(a, 16);
    a += __shfl_xor(a, 32);
    if (lane < 16) sig2[n * 16 + cd] = (_Float16)(a * di);   // pre-scale
}

// ---- layer-2 aggregate + b2 -> out ------------------------------------------
// one WAVE per node; lanes = (edge-group g in [0,8)) x (dword cd in [0,8)).
// masked single-round loop: ceil(dn/32) iters; deg<=32 nodes do ONE round.
__global__ __launch_bounds__(BS) void k_agg2(
    const _Float16* __restrict__ sig2, const int* __restrict__ row_start,
    const float* __restrict__ dinv, const int* __restrict__ col,
    const float* __restrict__ b2, int N, float* __restrict__ out) {
    int t = threadIdx.x;
    int lane = t & 63;
    int n = blockIdx.x * (BS / 64) + (t >> 6);
    if (n >= N) return;
    int g  = lane >> 3;              // edge group 0..7
    int cd = lane & 7;               // dword channel (2 fp16)
    const int* s2i = (const int*)sig2;
    int rs = __builtin_amdgcn_readfirstlane(row_start[n]);
    int re = __builtin_amdgcn_readfirstlane(row_start[n + 1]);
    int dn = re - rs;
    float a0 = 0.f, a1 = 0.f;
    int iters = (dn + 31) >> 5;
    int l32 = lane & 31;
    int colv = 0;
    if (iters > 0) {
        int idx = l32; if (idx > dn - 1) idx = dn - 1;
        colv = col[rs + idx];
    }
    for (int it = 0; it < iters; it++) {
        int e = it << 5;
        int coln = 0;
        if (it + 1 < iters) {
            int idx = e + 32 + l32; if (idx > dn - 1) idx = dn - 1;
            coln = col[rs + idx];
        }
        int s0 = __shfl(colv, g);
        int s1 = __shfl(colv, 8 + g);
        int s2 = __shfl(colv, 16 + g);
        int s3 = __shfl(colv, 24 + g);
        H2 u0, u1, u2, u3;
        u0.i = s2i[s0 * 8 + cd];
        u1.i = s2i[s1 * 8 + cd];
        u2.i = s2i[s2 * 8 + cd];
        u3.i = s2i[s3 * 8 + cd];
        float m0 = (e + g      < dn) ? 1.f : 0.f;
        float m1 = (e + 8 + g  < dn) ? 1.f : 0.f;
        float m2 = (e + 16 + g < dn) ? 1.f : 0.f;
        float m3 = (e + 24 + g < dn) ? 1.f : 0.f;
        a0 += (m0 * (float)u0.h[0] + m1 * (float)u1.h[0])
            + (m2 * (float)u2.h[0] + m3 * (float)u3.h[0]);
        a1 += (m0 * (float)u0.h[1] + m1 * (float)u1.h[1])
            + (m2 * (float)u2.h[1] + m3 * (float)u3.h[1]);
        colv = coln;
    }
    a0 += __shfl_xor(a0, 8); a0 += __shfl_xor(a0, 16); a0 += __shfl_xor(a0, 32);
    a1 += __shfl_xor(a1, 8); a1 += __shfl_xor(a1, 16); a1 += __shfl_xor(a1, 32);
    H2 us; us.i = s2i[n * 8 + cd];               // self-loop
    a0 += (float)us.h[0];
    a1 += (float)us.h[1];
    if (lane < 8) {
        float di = dinv[n];
        float2 b = ((const float2*)b2)[cd];
        float2 o;
        o.x = a0 * di + b.x;
        o.y = a1 * di + b.y;
        ((float2*)out)[n * 8 + cd] = o;
    }
}

extern "C" void kernel_launch(void* const* d_in, const int* in_sizes, int n_in,
                              void* d_out, int out_size, void* d_ws, size_t ws_size,
                              hipStream_t stream) {
    const int*   x   = (const int*)d_in[0];
    const int*   ei  = (const int*)d_in[1];
    const float* emb = (const float*)d_in[2];
    const float* W1  = (const float*)d_in[3];
    const float* b1  = (const float*)d_in[4];
    const float* W2  = (const float*)d_in[5];
    const float* b2  = (const float*)d_in[6];
    float* out = (float*)d_out;

    const int N = in_sizes[0];
    const int E = in_sizes[1] / 2;
    const int* srcp = ei;
    const int* dstp = ei + E;
    const int NBINS = (N + BIN - 1) >> BINSHIFT;   // 391 for N=100000
    const int L = NBINS * NBLK;
    const int nB2 = (L + BS - 1) / BS;

    auto al = [](size_t b) { return (b + 255) & ~size_t(255); };
    char* w = (char*)d_ws;
    auto carve = [&](size_t bytes) {
        void* p = (void*)w;
        w += al(bytes);
        return p;
    };
    // no unions: binsort writes sig1 while other blocks still read packed.
    int*   row_start = (int*)carve((size_t)(N + 1) * 4);
    float* dinv      = (float*)carve((size_t)N * 4);
    int*   col       = (int*)carve((size_t)E * 4);
    int*   histG     = (int*)carve((size_t)L * 4);
    int*   partial   = (int*)carve((size_t)L * 4);
    int*   bsum      = (int*)carve((size_t)nB2 * 4);
    int*   boff      = (int*)carve((size_t)nB2 * 4);
    int*   packed    = (int*)carve((size_t)E * 4);
    _Float16* sig1   = (_Float16*)carve((size_t)N * 32 * 2);
    _Float16* sig2   = (_Float16*)carve((size_t)N * 16 * 2);
    (void)ws_size; (void)n_in; (void)out_size;

    int gL = (L + BS - 1) / BS;
    k_hist<<<NBLK, BS, 0, stream>>>(dstp, E, NBINS, histG);
    k_scanA<<<gL, BS, 0, stream>>>(histG, L, partial, bsum);
    k_scanB<<<1, BS, 0, stream>>>(bsum, nB2, boff);
    k_binscatter<<<NBLK, BS, 0, stream>>>(srcp, dstp, E, NBINS, partial, boff, packed);
    k_binsort<<<NBINS, BS, 0, stream>>>(packed, partial, boff, NBINS, N, E,
                                        x, emb, W1, row_start, dinv, col, sig1);

    int gW = (N + 3) / 4;              // one wave (64 lanes) per node
    k_agg1mm2<<<gW, BS, 0, stream>>>(sig1, row_start, dinv, col, b1, W2, N, sig2);
    k_agg2<<<gW, BS, 0, stream>>>(sig2, row_start, dinv, col, b2, N, out);
}

// Round 12
// 159.379 us; speedup vs baseline: 1.3387x; 1.1345x over previous
//
#include <hip/hip_runtime.h>

// 2-layer GCN: h1 = emb[x] @ W1; agg+b1+relu; @ W2; agg+b2.
// CSR built per-launch via two-level binned counting sort (no global atomics).
// R12: agg kernels process 4 NODES PER WAVE (lane = node x channel) --
// R11 was epilogue-bound (~70 insts + 14 ds_bpermute per node at avg deg 16;
// VALUBusy 51%, 2M LDS conflicts). Per-lane full-channel ownership kills all
// aggregation reductions; GEMM h goes through a per-wave LDS buffer with
// W2 column in 32 VGPRs. Build side = R11 (int4 reads, 256-node bins,
// fused mm1, packed src|dstl<<18).

#define BS   256
#define NBLK 256          // blocks for hist/binscatter (MUST stay 256: idx>>8==bin)
#define BINSHIFT 8        // 256 nodes per bin
#define BIN  256
#define MAXBINS 512
#define BINCAP 4608       // LDS packed staging (mean bin = 4092, sigma ~64)

union H2 { int i; _Float16 h[2]; };

// ---- pass A: per-block histograms of dst bins (int4 reads, grid-stride) -----
__global__ void k_hist(const int* __restrict__ dst, int E, int NBINS,
                       int* __restrict__ histG) {
    __shared__ int h[MAXBINS];
    int t = threadIdx.x;
    for (int i = t; i < NBINS; i += BS) h[i] = 0;
    __syncthreads();
    int E4 = E >> 2;
    const int4* d4 = (const int4*)dst;
    for (int i = blockIdx.x * BS + t; i < E4; i += NBLK * BS) {
        int4 d = d4[i];
        atomicAdd(&h[d.x >> BINSHIFT], 1);
        atomicAdd(&h[d.y >> BINSHIFT], 1);
        atomicAdd(&h[d.z >> BINSHIFT], 1);
        atomicAdd(&h[d.w >> BINSHIFT], 1);
    }
    if (blockIdx.x == 0 && t < (E & 3))
        atomicAdd(&h[dst[(E4 << 2) + t] >> BINSHIFT], 1);
    __syncthreads();
    for (int i = t; i < NBINS; i += BS) histG[i * NBLK + blockIdx.x] = h[i];
}

// ---- hierarchical exclusive scan over L = NBINS*NBLK ints -------------------
__global__ void k_scanA(const int* __restrict__ in, int L,
                        int* __restrict__ partial, int* __restrict__ bsum) {
    __shared__ int s[BS];
    int t = threadIdx.x;
    int i = blockIdx.x * BS + t;
    int v = (i < L) ? in[i] : 0;
    s[t] = v;
    __syncthreads();
    for (int off = 1; off < BS; off <<= 1) {
        int add = (t >= off) ? s[t - off] : 0;
        __syncthreads();
        s[t] += add;
        __syncthreads();
    }
    if (i < L) partial[i] = s[t] - v;
    if (t == BS - 1) bsum[blockIdx.x] = s[BS - 1];
}

__global__ void k_scanB(const int* __restrict__ bsum, int nB, int* __restrict__ boff) {
    __shared__ int s[BS];
    int t = threadIdx.x;
    int PER = (nB + BS - 1) / BS;
    int loc[8];
    int base = t * PER;
    int sum = 0;
    for (int j = 0; j < PER && j < 8; j++) {
        int idx = base + j;
        int v = (idx < nB) ? bsum[idx] : 0;
        loc[j] = sum;
        sum += v;
    }
    s[t] = sum;
    __syncthreads();
    for (int off = 1; off < BS; off <<= 1) {
        int add = (t >= off) ? s[t - off] : 0;
        __syncthreads();
        s[t] += add;
        __syncthreads();
    }
    int ex = s[t] - sum;
    for (int j = 0; j < PER && j < 8; j++) {
        int idx = base + j;
        if (idx < nB) boff[idx] = ex + loc[j];
    }
}

// ---- pass C: scatter edges into bin-partitioned order (LDS cursors only) ----
// ONE packed 4B write per edge: src | dstLocal<<18  (src < 2^18).
__global__ void k_binscatter(const int* __restrict__ src, const int* __restrict__ dst,
                             int E, int NBINS, const int* __restrict__ partial,
                             const int* __restrict__ boff, int* __restrict__ packed) {
    __shared__ int cur[MAXBINS];
    int t = threadIdx.x;
    for (int i = t; i < NBINS; i += BS)
        cur[i] = partial[i * NBLK + blockIdx.x] + boff[i];
    __syncthreads();
    int E4 = E >> 2;
    const int4* s4 = (const int4*)src;
    const int4* d4 = (const int4*)dst;
    for (int i = blockIdx.x * BS + t; i < E4; i += NBLK * BS) {
        int4 s = s4[i];
        int4 d = d4[i];
        int p0 = atomicAdd(&cur[d.x >> BINSHIFT], 1);
        packed[p0] = s.x | ((d.x & (BIN - 1)) << 18);
        int p1 = atomicAdd(&cur[d.y >> BINSHIFT], 1);
        packed[p1] = s.y | ((d.y & (BIN - 1)) << 18);
        int p2 = atomicAdd(&cur[d.z >> BINSHIFT], 1);
        packed[p2] = s.z | ((d.z & (BIN - 1)) << 18);
        int p3 = atomicAdd(&cur[d.w >> BINSHIFT], 1);
        packed[p3] = s.w | ((d.w & (BIN - 1)) << 18);
    }
    if (blockIdx.x == 0 && t < (E & 3)) {
        int e = (E4 << 2) + t;
        int d = dst[e];
        int p = atomicAdd(&cur[d >> BINSHIFT], 1);
        packed[p] = src[e] | ((d & (BIN - 1)) << 18);
    }
}

// ---- pass D: per-bin counting sort (staged in LDS) + fused mm1 --------------
__global__ void k_binsort(const int* __restrict__ packed,
                          const int* __restrict__ partial, const int* __restrict__ boff,
                          int NBINS, int N, int E,
                          const int* __restrict__ x, const float* __restrict__ emb,
                          const float* __restrict__ W1,
                          int* __restrict__ row_start, float* __restrict__ dinv,
                          int* __restrict__ col, _Float16* __restrict__ sig1) {
    __shared__ int buf[BINCAP];                  // 18 KB staging
    __shared__ int ldeg[BIN];
    __shared__ int lrs[BIN];
    __shared__ int cur[BIN];
    __shared__ float sW[512];                    // W1 (16x32)
    int b = blockIdx.x;
    int t = threadIdx.x;
    int node0 = b << BINSHIFT;
    int e0 = partial[b * NBLK] + boff[b];
    int e1 = (b + 1 < NBINS) ? (partial[(b + 1) * NBLK] + boff[b + 1]) : E;
    int cnt = e1 - e0;
    bool fits = (cnt <= BINCAP);                 // uniform per block
    if (b == 0 && t == 0) row_start[N] = E;      // sentinel
    sW[t] = W1[t];
    sW[t + 256] = W1[t + 256];
    ldeg[t] = 0;
    if (fits)
        for (int i = t; i < cnt; i += BS) buf[i] = packed[e0 + i];
    __syncthreads();
    for (int i = t; i < cnt; i += BS) {
        int v = fits ? buf[i] : packed[e0 + i];
        atomicAdd(&ldeg[((unsigned)v >> 18) & (BIN - 1)], 1);
    }
    __syncthreads();
    lrs[t] = ldeg[t];
    __syncthreads();
    for (int off = 1; off < BIN; off <<= 1) {
        int add = (t >= off) ? lrs[t - off] : 0;
        __syncthreads();
        lrs[t] += add;
        __syncthreads();
    }
    int myDeg = ldeg[t];
    int ex = lrs[t] - myDeg;
    cur[t] = ex;
    int n = node0 + t;                           // one node per thread
    float di = rsqrtf((float)(myDeg + 1));
    if (n < N) {
        row_start[n] = e0 + ex;
        dinv[n] = di;
    }
    __syncthreads();
    for (int i = t; i < cnt; i += BS) {
        int v = fits ? buf[i] : packed[e0 + i];
        int pos = atomicAdd(&cur[((unsigned)v >> 18) & (BIN - 1)], 1);
        col[e0 + pos] = v & 0x3FFFF;
    }
    // ---- fused mm1 for this bin's 256 nodes ----
    if (n < N) {
        const float4* er = (const float4*)(emb + (size_t)x[n] * 16);
        float4 ra = er[0], rb = er[1], rc = er[2], rd = er[3];
        float ev[16] = {ra.x, ra.y, ra.z, ra.w, rb.x, rb.y, rb.z, rb.w,
                        rc.x, rc.y, rc.z, rc.w, rd.x, rd.y, rd.z, rd.w};
        int4* s1o = (int4*)sig1;
        #pragma unroll
        for (int cq = 0; cq < 4; cq++) {
            H2 pk[4];
            #pragma unroll
            for (int dw = 0; dw < 4; dw++) {
                int c = cq * 8 + dw * 2;
                float acc0 = 0.f, acc1 = 0.f;
                #pragma unroll
                for (int k = 0; k < 16; k++) {
                    acc0 += ev[k] * sW[k * 32 + c];
                    acc1 += ev[k] * sW[k * 32 + c + 1];
                }
                pk[dw].h[0] = (_Float16)(acc0 * di);
                pk[dw].h[1] = (_Float16)(acc1 * di);
            }
            int4 pv;
            pv.x = pk[0].i; pv.y = pk[1].i; pv.z = pk[2].i; pv.w = pk[3].i;
            s1o[(size_t)n * 4 + cq] = pv;
        }
    }
}

// ---- fused layer-1 aggregate + b1 + relu + GEMM W2 -> sig2 (fp16) -----------
// 4 NODES per wave: lane = (node g in [0,4)) x (dword-channel cd in [0,16)).
// Each lane owns its channels end-to-end: no aggregation reductions, no
// final reduce. GEMM via per-wave LDS h-buffer + W2 column in 32 VGPRs.
__global__ __launch_bounds__(BS) void k_agg1mm2(
    const _Float16* __restrict__ sig1, const int* __restrict__ row_start,
    const float* __restrict__ dinv, const int* __restrict__ col,
    const float* __restrict__ b1, const float* __restrict__ W2,
    int N, _Float16* __restrict__ sig2) {
    __shared__ float hbuf[4][4][36];   // [wave][node][32 ch + pad to 16B mult]
    int t = threadIdx.x;
    int lane = t & 63;
    int wid = t >> 6;
    int g  = lane >> 4;                // node within wave
    int cd = lane & 15;                // dword channel (2 fp16)
    int n = blockIdx.x * 16 + wid * 4 + g;
    int nld = (n < N) ? n : N - 1;
    int rs = row_start[nld];
    int re = row_start[nld + 1];
    int dn = (n < N) ? (re - rs) : 0;
    int dnm1 = (dn > 0) ? dn - 1 : 0;
    int dm = dn;                       // wave max degree
    dm = max(dm, __shfl_xor(dm, 16));
    dm = max(dm, __shfl_xor(dm, 32));
    // W2 column preload: w2c[k] = W2[k][cd] (L1-hot broadcast lines)
    float w2c[32];
    #pragma unroll
    for (int k = 0; k < 32; k++) w2c[k] = W2[k * 16 + cd];
    const int* s1i = (const int*)sig1;
    float a0 = 0.f, a1 = 0.f;
    int iters = (dm + 3) >> 2;
    int slot = cd & 3;
    int bidx = lane & 48;              // group base lane
    for (int it = 0; it < iters; it++) {
        int e = it << 2;
        int idx = e + slot; if (idx > dnm1) idx = dnm1;
        int colv = col[rs + idx];      // 4 distinct addrs/group, 1 line
        int s0 = __shfl(colv, bidx + 0);
        int s1 = __shfl(colv, bidx + 1);
        int s2 = __shfl(colv, bidx + 2);
        int s3 = __shfl(colv, bidx + 3);
        int u0 = s1i[s0 * 16 + cd];    // 4 rows (64B lines) per inst
        int u1 = s1i[s1 * 16 + cd];
        int u2 = s1i[s2 * 16 + cd];
        int u3 = s1i[s3 * 16 + cd];
        u0 = (e + 0 < dn) ? u0 : 0;    // 0x0 == +0.0 fp16 pair
        u1 = (e + 1 < dn) ? u1 : 0;
        u2 = (e + 2 < dn) ? u2 : 0;
        u3 = (e + 3 < dn) ? u3 : 0;
        H2 p0, p1, p2, p3;
        p0.i = u0; p1.i = u1; p2.i = u2; p3.i = u3;
        a0 += ((float)p0.h[0] + (float)p1.h[0]) + ((float)p2.h[0] + (float)p3.h[0]);
        a1 += ((float)p0.h[1] + (float)p1.h[1]) + ((float)p2.h[1] + (float)p3.h[1]);
    }
    {   // self-loop (pre-scaled row)
        H2 p; p.i = s1i[nld * 16 + cd];
        a0 += (float)p.h[0];
        a1 += (float)p.h[1];
    }
    float di = dinv[nld];
    float2 b = ((const float2*)b1)[cd];
    float h0 = fmaxf(a0 * di + b.x, 0.f);
    float h1 = fmaxf(a1 * di + b.y, 0.f);
    float* hb = hbuf[wid][g];
    *(float2*)&hb[2 * cd] = make_float2(h0, h1);
    // same-wave LDS produce->consume: in-order ds ops + lgkmcnt, no barrier
    float a = 0.f;
    #pragma unroll
    for (int k = 0; k < 32; k += 4) {
        float4 hv = *(const float4*)&hb[k];    // broadcast within group
        a = fmaf(hv.x, w2c[k],     a);
        a = fmaf(hv.y, w2c[k + 1], a);
        a = fmaf(hv.z, w2c[k + 2], a);
        a = fmaf(hv.w, w2c[k + 3], a);
    }
    if (n < N) sig2[(size_t)n * 16 + cd] = (_Float16)(a * di);   // pre-scale
}

// ---- layer-2 aggregate + b2 -> out ------------------------------------------
// 4 NODES per wave: lane = (node g) x (edge-half e2) x (dword cd in [0,8)).
// Only one xor8 reduction remains; out written directly per lane.
__global__ __launch_bounds__(BS) void k_agg2(
    const _Float16* __restrict__ sig2, const int* __restrict__ row_start,
    const float* __restrict__ dinv, const int* __restrict__ col,
    const float* __restrict__ b2, int N, float* __restrict__ out) {
    int t = threadIdx.x;
    int lane = t & 63;
    int g  = lane >> 4;                // node within wave
    int e2 = (lane >> 3) & 1;          // edge half
    int cd = lane & 7;                 // dword channel (2 fp16)
    int n = blockIdx.x * 16 + (t >> 6) * 4 + g;
    int nld = (n < N) ? n : N - 1;
    int rs = row_start[nld];
    int re = row_start[nld + 1];
    int dn = (n < N) ? (re - rs) : 0;
    int dnm1 = (dn > 0) ? dn - 1 : 0;
    int dm = dn;
    dm = max(dm, __shfl_xor(dm, 16));
    dm = max(dm, __shfl_xor(dm, 32));
    const int* s2i = (const int*)sig2;
    float a0 = 0.f, a1 = 0.f;
    int iters = (dm + 7) >> 3;
    int slot = lane & 7;               // this lane's col slot (0..7)
    int bidx = lane & 48;
    for (int it = 0; it < iters; it++) {
        int e = it << 3;
        int idx = e + slot; if (idx > dnm1) idx = dnm1;
        int colv = col[rs + idx];      // 8 distinct addrs/group, 1 line
        #pragma unroll
        for (int j = 0; j < 4; j++) {
            int sl = 2 * j + e2;
            int sv = __shfl(colv, bidx + sl);
            int u = s2i[sv * 8 + cd];  // 8 rows (32B) per inst
            u = (e + sl < dn) ? u : 0;
            H2 p; p.i = u;
            a0 += (float)p.h[0];
            a1 += (float)p.h[1];
        }
    }
    a0 += __shfl_xor(a0, 8);           // combine edge halves
    a1 += __shfl_xor(a1, 8);
    {   // self-loop
        H2 p; p.i = s2i[nld * 8 + cd];
        a0 += (float)p.h[0];
        a1 += (float)p.h[1];
    }
    if (n < N && e2 == 0) {
        float di = dinv[nld];
        float2 b = ((const float2*)b2)[cd];
        float2 o;
        o.x = a0 * di + b.x;
        o.y = a1 * di + b.y;
        ((float2*)out)[(size_t)n * 8 + cd] = o;
    }
}

extern "C" void kernel_launch(void* const* d_in, const int* in_sizes, int n_in,
                              void* d_out, int out_size, void* d_ws, size_t ws_size,
                              hipStream_t stream) {
    const int*   x   = (const int*)d_in[0];
    const int*   ei  = (const int*)d_in[1];
    const float* emb = (const float*)d_in[2];
    const float* W1  = (const float*)d_in[3];
    const float* b1  = (const float*)d_in[4];
    const float* W2  = (const float*)d_in[5];
    const float* b2  = (const float*)d_in[6];
    float* out = (float*)d_out;

    const int N = in_sizes[0];
    const int E = in_sizes[1] / 2;
    const int* srcp = ei;
    const int* dstp = ei + E;
    const int NBINS = (N + BIN - 1) >> BINSHIFT;   // 391 for N=100000
    const int L = NBINS * NBLK;
    const int nB2 = (L + BS - 1) / BS;

    auto al = [](size_t b) { return (b + 255) & ~size_t(255); };
    char* w = (char*)d_ws;
    auto carve = [&](size_t bytes) {
        void* p = (void*)w;
        w += al(bytes);
        return p;
    };
    // no unions: binsort writes sig1 while other blocks still read packed.
    int*   row_start = (int*)carve((size_t)(N + 1) * 4);
    float* dinv      = (float*)carve((size_t)N * 4);
    int*   col       = (int*)carve((size_t)(E + 256) * 4);  // +pad for clamped reads
    int*   histG     = (int*)carve((size_t)L * 4);
    int*   partial   = (int*)carve((size_t)L * 4);
    int*   bsum      = (int*)carve((size_t)nB2 * 4);
    int*   boff      = (int*)carve((size_t)nB2 * 4);
    int*   packed    = (int*)carve((size_t)E * 4);
    _Float16* sig1   = (_Float16*)carve((size_t)N * 32 * 2);
    _Float16* sig2   = (_Float16*)carve((size_t)N * 16 * 2);
    (void)ws_size; (void)n_in; (void)out_size;

    int gL = (L + BS - 1) / BS;
    k_hist<<<NBLK, BS, 0, stream>>>(dstp, E, NBINS, histG);
    k_scanA<<<gL, BS, 0, stream>>>(histG, L, partial, bsum);
    k_scanB<<<1, BS, 0, stream>>>(bsum, nB2, boff);
    k_binscatter<<<NBLK, BS, 0, stream>>>(srcp, dstp, E, NBINS, partial, boff, packed);
    k_binsort<<<NBINS, BS, 0, stream>>>(packed, partial, boff, NBINS, N, E,
                                        x, emb, W1, row_start, dinv, col, sig1);

    int gA = (N + 15) / 16;            // 4 waves x 4 nodes per block
    k_agg1mm2<<<gA, BS, 0, stream>>>(sig1, row_start, dinv, col, b1, W2, N, sig2);
    k_agg2<<<gA, BS, 0, stream>>>(sig2, row_start, dinv, col, b2, N, out);
}